// Round 11
// baseline (181.791 us; speedup 1.0000x reference)
//
#include <hip/hip_runtime.h>
#include <math.h>

typedef __attribute__((ext_vector_type(8))) short short8;
typedef __attribute__((ext_vector_type(4))) float float4v;
typedef __attribute__((ext_vector_type(4))) unsigned short ushort4v;

static __device__ __forceinline__ unsigned short f2bf(float f) {
    union { float f; unsigned u; } v; v.f = f;
    unsigned u = v.u;
    return (unsigned short)((u + 0x7fffu + ((u >> 16) & 1u)) >> 16);
}
static __device__ __forceinline__ float bf2f(unsigned short h) {
    union { unsigned u; float f; } v; v.u = ((unsigned)h) << 16;
    return v.f;
}
static __device__ __forceinline__ unsigned pk2(float a, float b) {
    return (unsigned)f2bf(a) | ((unsigned)f2bf(b) << 16);
}
// XOR-swizzled address into [pos][32] bf16 rows (8-ushort chunks):
// chunk c at row pos lives at physical chunk (c ^ pos) & 3. Returns ushort idx.
static __device__ __forceinline__ int swz(int pos, int chunk) {
    return (pos << 5) + (((chunk ^ pos) & 3) << 3);
}

// ---------------------------------------------------------------------------
// Graph structure (compile-time), matching Python enumeration order.
// ---------------------------------------------------------------------------
struct AdjT {
    int src[120];
    int dst[120];
    int cnt[36];
    int idx[36][4];
    int ostart[36];
    int ocnt[36];
};

constexpr AdjT build_adj() {
    AdjT a{};
    const int ddx[4] = {-1, 0, 0, 1};
    const int ddy[4] = {0, -1, 1, 0};
    int ne = 0;
    for (int i = 0; i < 6; i++)
        for (int j = 0; j < 6; j++)
            for (int d = 0; d < 4; d++) {
                int x = i + ddx[d], y = j + ddy[d];
                if (x >= 0 && x < 6 && y >= 0 && y < 6) {
                    a.src[ne] = j * 6 + i;
                    a.dst[ne] = y * 6 + x;
                    ne++;
                }
            }
    for (int n = 0; n < 36; n++) {
        a.cnt[n] = 0;
        for (int e = 0; e < 120; e++)
            if (a.dst[e] == n) a.idx[n][a.cnt[n]++] = e;
    }
    for (int n = 0; n < 36; n++) { a.ostart[n] = 0; a.ocnt[n] = 0; }
    for (int e = 0; e < 120; e++) {
        a.ocnt[a.src[e]]++;
        if (e == 0 || a.src[e] != a.src[e - 1]) a.ostart[a.src[e]] = e;
    }
    return a;
}

__device__ constexpr AdjT ADJC = build_adj();
__device__ constexpr int G16_START[17] =
    {0, 3, 6, 9, 12, 14, 16, 18, 20, 22, 24, 26, 28, 30, 32, 34, 36};

// ---------------------------------------------------------------------------
// K0: merged weight prep (verified R9/R10). Column-interleaved conv B-frags.
// ---------------------------------------------------------------------------
__global__ __launch_bounds__(256) void k_prepall(
    const float* __restrict__ w1, const float* __restrict__ w2,
    const float* __restrict__ w3, const float* __restrict__ w4,
    const float* __restrict__ cnw1, const float* __restrict__ epw1,
    const float* __restrict__ cnw2, const float* __restrict__ epw2,
    unsigned short* __restrict__ wp1, unsigned short* __restrict__ wp2,
    unsigned short* __restrict__ wp3, unsigned short* __restrict__ wp4,
    unsigned short* __restrict__ wph1, unsigned short* __restrict__ wpcn2,
    unsigned short* __restrict__ wpep2) {
    int e = blockIdx.x * 256 + threadIdx.x;
    if (e < 180224) {
        if (e < 25600) {
            int j = e & 7, lane = (e >> 3) & 63, ct = (e >> 9) & 1, t = e >> 10;
            int co = 2 * (lane & 15) + ct, ci = (lane >> 4) * 8 + j;
            wp2[e] = f2bf(w2[co * 800 + ci * 25 + t]);
        } else if (e < 76800) {
            int e3 = e - 25600;
            int j = e3 & 7, lane = (e3 >> 3) & 63, nt = (e3 >> 9) & 3, t = e3 >> 11;
            int co = 4 * (lane & 15) + nt, ci = (lane >> 4) * 8 + j;
            wp3[e3] = f2bf(w3[(co * 32 + ci) * 25 + t]);
        } else if (e < 179200) {
            int e4 = e - 76800;
            int j = e4 & 7, lane = (e4 >> 3) & 63, nt = (e4 >> 9) & 3;
            int ks = (e4 >> 11) & 1, t = e4 >> 12;
            int co = 4 * (lane & 15) + nt, ci = ks * 32 + (lane >> 4) * 8 + j;
            wp4[e4] = f2bf(w4[(co * 64 + ci) * 25 + t]);
        } else {
            int e1 = e - 179200;
            int j = e1 & 7, lane = (e1 >> 3) & 63, nt = (e1 >> 9) & 1;
            int n = lane & 15, q = lane >> 4;
            int k = q * 8 + j;
            int co = 2 * n + nt;
            wp1[e1] = (k < 25) ? f2bf(w1[co * 25 + k]) : (unsigned short)0;
        }
    } else {
        int eh = e - 180224;
        if (eh < 131072) {
            int j = eh & 7, lane = (eh >> 3) & 63, nt = (eh >> 9) & 31, kt = eh >> 14;
            int c = nt * 16 + (lane & 15);
            int k = kt * 32 + ((lane >> 4) << 3) + j;
            float v = (c < 256) ? cnw1[c * 256 + k] : epw1[(c - 256) * 256 + k];
            wph1[eh] = f2bf(v);
        } else if (eh < 163840) {
            int e2 = eh - 131072;
            int j = e2 & 7, lane = (e2 >> 3) & 63, nt = (e2 >> 9) & 7, kt = e2 >> 12;
            int c = nt * 16 + (lane & 15);
            int k = kt * 32 + ((lane >> 4) << 3) + j;
            wpcn2[e2] = f2bf(c < 120 ? cnw2[c * 256 + k] : 0.f);
        } else {
            int e3 = eh - 163840;
            int j = e3 & 7, lane = (e3 >> 3) & 63, idx = e3 >> 9;
            int kt = idx / 3, nt = idx - kt * 3;
            int c = nt * 16 + (lane & 15);
            int k = kt * 32 + ((lane >> 4) << 3) + j;
            wpep2[e3] = f2bf(c < 36 ? epw2[c * 256 + k] : 0.f);
        }
    }
}

// ---------------------------------------------------------------------------
// K_CONVALL: whole CNN in one kernel. R11: XOR-swizzled [784][32] conv1 buffer
// (no padding) + bf16 image tile -> LDS 51.3 KB -> 3 blocks/CU (6 waves/SIMD).
// Regions of s_buf (ushort idx):
//   conv1 out  [784][32] swizzled    [0, 25088)
//   conv2 stage[576][32] swizzled    [0, 18432)   (conv1 dead after conv2)
//   p2         [144][40] plain       [18432, 24192)
//   s_c3       [64][72] plain        [0, 4608)    (stage dead after pool)
//   s_c4 f32   [16][68]              ushort [8192, 10368)
// ---------------------------------------------------------------------------
__global__ __launch_bounds__(512, 6) void k_convall(
    const float* __restrict__ img, const float* __restrict__ b1,
    const unsigned short* __restrict__ wp1,
    const unsigned short* __restrict__ wp2, const float* __restrict__ b2,
    const unsigned short* __restrict__ wp3, const float* __restrict__ b3,
    const unsigned short* __restrict__ wp4, const float* __restrict__ b4,
    unsigned short* __restrict__ emb) {
    __shared__ unsigned short s_imgbf[32 * 36];
    __shared__ unsigned short s_buf[25088];
    const int b = blockIdx.x, tid = threadIdx.x;
    const int lane = tid & 63, wave = tid >> 6;
    const int m = lane & 15, quad = lane >> 4;
    const int P2O = 18432;

    // stage full image as bf16 (first 256 threads, float4 -> 4x bf16 b64 write)
    if (tid < 256) {
        float4 t = ((const float4*)(img + (size_t)b * 1024))[tid];
        ushort4v pkv;
        pkv[0] = f2bf(t.x); pkv[1] = f2bf(t.y);
        pkv[2] = f2bf(t.z); pkv[3] = f2bf(t.w);
        *(ushort4v*)(s_imgbf + (tid >> 3) * 36 + (tid & 7) * 4) = pkv;
    }

    // conv1 B-frags + per-lane tap gather offsets (K=25 pad 32)
    short8 w1b0 = ((const short8*)wp1)[lane];
    short8 w1b1 = ((const short8*)wp1)[64 + lane];
    const float c1b0 = b1[2 * m], c1b1 = b1[2 * m + 1];
    int toff1[8];
    unsigned short vm1[8];
#pragma unroll
    for (int j = 0; j < 8; j++) {
        int k = quad * 8 + j;
        int kk = (k < 25) ? k : 0;
        int ky = kk / 5, kx = kk - ky * 5;
        toff1[j] = ky * 36 + kx;
        vm1[j] = (k < 25) ? (unsigned short)0xFFFFu : (unsigned short)0;
    }
    // conv2 B-frag prefetch
    const short8* wq2 = (const short8*)wp2;
    short8 bw0 = wq2[lane];
    short8 bw1 = wq2[64 + lane];

    __syncthreads();

    // ---- conv1 via MFMA: 49 Mtiles, stride 8 over waves; swizzled staging ----
    for (int mt = wave; mt < 49; mt += 8) {
        int pos = mt * 16 + m;
        int y = pos / 28, x = pos - y * 28;
        const unsigned short* wb = s_imgbf + y * 36 + x;
        short8 av;
#pragma unroll
        for (int j = 0; j < 8; j++)
            av[j] = (short)(wb[toff1[j]] & vm1[j]);
        float4v a0 = {c1b0, c1b0, c1b0, c1b0};
        float4v a1 = {c1b1, c1b1, c1b1, c1b1};
        a0 = __builtin_amdgcn_mfma_f32_16x16x32_bf16(av, w1b0, a0, 0, 0, 0);
        a1 = __builtin_amdgcn_mfma_f32_16x16x32_bf16(av, w1b1, a1, 0, 0, 0);
        int pb = mt * 16 + quad * 4;
#pragma unroll
        for (int r = 0; r < 4; r++) {
            int row = pb + r;
            *(unsigned*)(s_buf + swz(row, m >> 2) + ((m & 3) << 1)) = pk2(a0[r], a1[r]);
        }
    }
    __syncthreads();

    // ---- conv2 tap-GEMM: 36 Mtiles -> waves 0-3: 5, waves 4-7: 4 ----
    const int nm2 = (wave < 4) ? 5 : 4;
    int bp[5];
#pragma unroll
    for (int i9 = 0; i9 < 5; i9++) {
        int M = i9 * 8 + wave;
        if (M > 35) M = 35;
        int p = M * 16 + m;
        int y2 = p / 24, x2 = p - y2 * 24;
        bp[i9] = y2 * 28 + x2;
    }
    float4v acc[5][2];
#pragma unroll
    for (int i9 = 0; i9 < 5; i9++) {
        acc[i9][0] = (float4v){0.f, 0.f, 0.f, 0.f};
        acc[i9][1] = (float4v){0.f, 0.f, 0.f, 0.f};
    }
    for (int t = 0; t < 25; t++) {
        short8 nb0, nb1;
        if (t < 24) {
            nb0 = wq2[(t + 1) * 128 + lane];
            nb1 = wq2[(t + 1) * 128 + 64 + lane];
        }
        const int ky = t / 5, kx = t - ky * 5;
        const int tp = ky * 28 + kx;
#pragma unroll
        for (int i9 = 0; i9 < 5; i9++) {
            if (i9 < nm2) {
                int p = bp[i9] + tp;
                short8 av = *(const short8*)(s_buf + swz(p, quad));
                acc[i9][0] = __builtin_amdgcn_mfma_f32_16x16x32_bf16(av, bw0, acc[i9][0], 0, 0, 0);
                acc[i9][1] = __builtin_amdgcn_mfma_f32_16x16x32_bf16(av, bw1, acc[i9][1], 0, 0, 0);
            }
        }
        if (t < 24) { bw0 = nb0; bw1 = nb1; }
    }
    __syncthreads();  // all conv2 A-reads done before stage overwrites

    // stage conv2 out: packed b32, swizzled [pos2][co]
#pragma unroll
    for (int i9 = 0; i9 < 5; i9++) {
        if (i9 < nm2) {
            int pb2 = (i9 * 8 + wave) * 16 + quad * 4;
#pragma unroll
            for (int r = 0; r < 4; r++) {
                int row = pb2 + r;
                *(unsigned*)(s_buf + swz(row, m >> 2) + ((m & 3) << 1)) =
                    pk2(acc[i9][0][r], acc[i9][1][r]);
            }
        }
    }
    __syncthreads();

    // pool 2x2 + bias2 -> p2 [144][40] plain at P2O
    for (int i = tid; i < 4608; i += 512) {
        int co = i & 31, pos12 = i >> 5;
        int prl = pos12 / 12, px = pos12 - prl * 12;
        int p00 = (prl * 2) * 24 + px * 2;
        int ch = co >> 3, cw = co & 7;
        float v0 = bf2f(s_buf[swz(p00, ch) + cw]);
        float v1 = bf2f(s_buf[swz(p00 + 1, ch) + cw]);
        float v2 = bf2f(s_buf[swz(p00 + 24, ch) + cw]);
        float v3 = bf2f(s_buf[swz(p00 + 25, ch) + cw]);
        float mx = fmaxf(fmaxf(v0, v1), fmaxf(v2, v3));
        s_buf[P2O + pos12 * 40 + co] = f2bf(mx + b2[co]);
    }
    __syncthreads();

    // ---- conv3: Mtile = wave>>1 (pos3 in 8x8 grid), Ntile half = wave&1 ----
    {
        int pos3 = (wave >> 1) * 16 + m;
        int y3 = pos3 >> 3, x3 = pos3 & 7;
        int a3 = P2O + (y3 * 12 + x3) * 40 + quad * 8;
        int nt0 = (wave & 1) * 2;
        float4v acc3[2];
        acc3[0] = (float4v){0.f, 0.f, 0.f, 0.f};
        acc3[1] = (float4v){0.f, 0.f, 0.f, 0.f};
        const short8* wq3 = (const short8*)wp3;
        short8 bw3[2];
        bw3[0] = wq3[nt0 * 64 + lane];
        bw3[1] = wq3[(nt0 + 1) * 64 + lane];
        for (int t = 0; t < 25; t++) {
            short8 nb3[2];
            if (t < 24) {
                nb3[0] = wq3[((t + 1) * 4 + nt0) * 64 + lane];
                nb3[1] = wq3[((t + 1) * 4 + nt0 + 1) * 64 + lane];
            }
            const int ky = t / 5, kx = t - ky * 5;
            short8 av = *(const short8*)(s_buf + a3 + (ky * 12 + kx) * 40);
            acc3[0] = __builtin_amdgcn_mfma_f32_16x16x32_bf16(av, bw3[0], acc3[0], 0, 0, 0);
            acc3[1] = __builtin_amdgcn_mfma_f32_16x16x32_bf16(av, bw3[1], acc3[1], 0, 0, 0);
            if (t < 24) { bw3[0] = nb3[0]; bw3[1] = nb3[1]; }
        }
        // stage s_c3 [64][72] (+bias3) at [0,4608): disjoint from p2 region,
        // stage region dead after pool -> no extra barrier needed.
        float bb0 = b3[4 * m + nt0], bb1 = b3[4 * m + nt0 + 1];
#pragma unroll
        for (int r = 0; r < 4; r++) {
            int row3 = (wave >> 1) * 16 + quad * 4 + r;
            *(unsigned*)(s_buf + row3 * 72 + 4 * m + nt0) =
                pk2(acc3[0][r] + bb0, acc3[1][r] + bb1);
        }
    }
    __syncthreads();

    // ---- conv4: waves 0-3 (Ntile = wave, 2 Ksteps); waves 4-7 idle ----
    if (wave < 4) {
        int y4 = m >> 2, x4 = m & 3;
        int a4 = (y4 * 8 + x4) * 72 + quad * 8;
        float4v acc4 = (float4v){0.f, 0.f, 0.f, 0.f};
        const short8* wq4 = (const short8*)wp4;
        short8 cw0 = wq4[(0 * 4 + wave) * 64 + lane];
        short8 cw1 = wq4[(1 * 4 + wave) * 64 + lane];
        for (int t = 0; t < 25; t++) {
            short8 n0, n1;
            if (t < 24) {
                n0 = wq4[(((t + 1) * 2) * 4 + wave) * 64 + lane];
                n1 = wq4[(((t + 1) * 2 + 1) * 4 + wave) * 64 + lane];
            }
            const int ky = t / 5, kx = t - ky * 5;
            const int toff = (ky * 8 + kx) * 72;
            short8 av0 = *(const short8*)(s_buf + a4 + toff);
            acc4 = __builtin_amdgcn_mfma_f32_16x16x32_bf16(av0, cw0, acc4, 0, 0, 0);
            short8 av1 = *(const short8*)(s_buf + a4 + toff + 32);
            acc4 = __builtin_amdgcn_mfma_f32_16x16x32_bf16(av1, cw1, acc4, 0, 0, 0);
            if (t < 24) { cw0 = n0; cw1 = n1; }
        }
        // s_c4 f32 [16][68] at ushort 8192 — disjoint from s_c3 [0,4608)
        float* s_c4 = (float*)(s_buf + 8192);
#pragma unroll
        for (int r = 0; r < 4; r++)
            s_c4[(quad * 4 + r) * 68 + 4 * m + wave] = acc4[r];
    }
    __syncthreads();

    // emb epilogue: tid = co*4 + pp; pool 2x2 + bias4 + flatten
    if (tid < 256) {
        const float* s_c4 = (const float*)(s_buf + 8192);
        int co = tid >> 2, pp = tid & 3;
        int ppy = pp >> 1, ppx = pp & 1;
        float v0 = s_c4[((2 * ppy) * 4 + 2 * ppx) * 68 + co];
        float v1 = s_c4[((2 * ppy) * 4 + 2 * ppx + 1) * 68 + co];
        float v2 = s_c4[((2 * ppy + 1) * 4 + 2 * ppx) * 68 + co];
        float v3 = s_c4[((2 * ppy + 1) * 4 + 2 * ppx + 1) * 68 + co];
        emb[(size_t)b * 256 + tid] =
            f2bf(fmaxf(fmaxf(v0, v1), fmaxf(v2, v3)) + b4[co]);
    }
}

// ---------------------------------------------------------------------------
// K5: fused heads (MFMA) + DAMP recurrence (verified R4-R10).
// Phase-3 uses wave-local sync (all comm intra-wave; row = tid>>4).
// ---------------------------------------------------------------------------
__global__ __launch_bounds__(256) void k_heads(
    const unsigned short* __restrict__ emb,
    const unsigned short* __restrict__ wph1,
    const float* __restrict__ cn_b1, const float* __restrict__ ep_b1,
    const unsigned short* __restrict__ wpcn2, const float* __restrict__ cn_b2,
    const unsigned short* __restrict__ wpep2, const float* __restrict__ ep_b2,
    float* __restrict__ out) {
    __shared__ unsigned short s_hid[16 * 520];
    __shared__ float s_conn[120 * 17];
    __shared__ float s_rec0[120 * 17];
    __shared__ float s_rec1[120 * 17];
    __shared__ float s_ep[36 * 17];
    const int tid = threadIdx.x;
    const int lane = tid & 63, wave = tid >> 6;
    const int m = lane & 15, q = lane >> 4;
    const int b0 = blockIdx.x * 16;

    float4v acc[8];
#pragma unroll
    for (int i = 0; i < 8; i++) acc[i] = (float4v){0.f, 0.f, 0.f, 0.f};
    const short8* wp1 = (const short8*)wph1;
    for (int kt = 0; kt < 8; kt++) {
        short8 av = *(const short8*)(emb + (size_t)(b0 + m) * 256 + kt * 32 + q * 8);
#pragma unroll
        for (int ntl = 0; ntl < 8; ntl++) {
            int nt = wave * 8 + ntl;
            short8 bv = wp1[(kt * 32 + nt) * 64 + lane];
            acc[ntl] = __builtin_amdgcn_mfma_f32_16x16x32_bf16(av, bv, acc[ntl], 0, 0, 0);
        }
    }
#pragma unroll
    for (int ntl = 0; ntl < 8; ntl++) {
        int c = (wave * 8 + ntl) * 16 + m;
        float bb = (c < 256) ? cn_b1[c] : ep_b1[c - 256];
#pragma unroll
        for (int r = 0; r < 4; r++)
            s_hid[(q * 4 + r) * 520 + c] = f2bf(fmaxf(acc[ntl][r] + bb, 0.f));
    }
    __syncthreads();

    for (int job = wave; job < 11; job += 4) {
        const bool isconn = job < 8;
        const int koff = isconn ? 0 : 256;
        float4v a2 = (float4v){0.f, 0.f, 0.f, 0.f};
        for (int kt = 0; kt < 8; kt++) {
            short8 av = *(const short8*)(s_hid + m * 520 + koff + kt * 32 + q * 8);
            short8 bv = isconn
                ? ((const short8*)wpcn2)[(kt * 8 + job) * 64 + lane]
                : ((const short8*)wpep2)[(kt * 3 + (job - 8)) * 64 + lane];
            a2 = __builtin_amdgcn_mfma_f32_16x16x32_bf16(av, bv, a2, 0, 0, 0);
        }
        int c = (isconn ? job : (job - 8)) * 16 + m;
        float bb = isconn ? (c < 120 ? cn_b2[c] : 0.f) : (c < 36 ? ep_b2[c] : 0.f);
#pragma unroll
        for (int r = 0; r < 4; r++) {
            float v = 1.f / (1.f + __expf(-(a2[r] + bb)));
            int row = q * 4 + r;
            if (isconn) {
                if (c < 120) { s_conn[c * 17 + row] = v; s_rec0[c * 17 + row] = v; }
            } else {
                if (c < 36) s_ep[c * 17 + row] = v;
            }
        }
    }
    __syncthreads();

    const int row = tid >> 4, g = tid & 15;
    const int ns = G16_START[g];
    const int nodecnt = G16_START[g + 1] - ns;
    int ie[3][4], icnt[3], os[3], oc[3];
    float cr[3][4];
#pragma unroll
    for (int s = 0; s < 3; s++) {
        if (s < nodecnt) {
            int n = ns + s;
            icnt[s] = ADJC.cnt[n];
#pragma unroll
            for (int qx = 0; qx < 4; qx++) ie[s][qx] = ADJC.idx[n][qx];
            os[s] = ADJC.ostart[n];
            oc[s] = ADJC.ocnt[n];
#pragma unroll
            for (int oe = 0; oe < 4; oe++)
                cr[s][oe] = (oe < oc[s]) ? s_conn[(os[s] + oe) * 17 + row] : 0.f;
        } else {
            icnt[s] = 0; oc[s] = 0; os[s] = 0;
#pragma unroll
            for (int qx = 0; qx < 4; qx++) ie[s][qx] = 0;
#pragma unroll
            for (int oe = 0; oe < 4; oe++) cr[s][oe] = 0.f;
        }
    }
    float old0 = (g == 0) ? s_conn[0 * 17 + row] : 0.f;

    for (int it = 0; it < 36; it++) {
        const float* cur = (it & 1) ? s_rec1 : s_rec0;
        float* nxt = (it & 1) ? s_rec0 : s_rec1;
#pragma unroll
        for (int s = 0; s < 3; s++) {
            float sum = 0.f;
#pragma unroll
            for (int qx = 0; qx < 4; qx++)
                sum += (qx < icnt[s]) ? cur[ie[s][qx] * 17 + row] : 0.f;
            sum = fminf(sum, 1.f);
#pragma unroll
            for (int oe = 0; oe < 4; oe++) {
                if (oe < oc[s]) {
                    int e = os[s] + oe;
                    float nv = sum * cr[s][oe];
                    nxt[e * 17 + row] = nv;
                    if (g == 0 && s == 0 && oe == 0)
                        old0 = fminf(old0 + nv, 1.f);
                }
            }
        }
        __asm__ volatile("s_waitcnt lgkmcnt(0)" ::: "memory");
    }

    if (g == 0)
        out[b0 + row] = old0 * s_ep[0 * 17 + row] * s_ep[6 * 17 + row];
}

// ---------------------------------------------------------------------------
extern "C" void kernel_launch(void* const* d_in, const int* in_sizes, int n_in,
                              void* d_out, int out_size, void* d_ws, size_t ws_size,
                              hipStream_t stream) {
    const float* image = (const float*)d_in[0];
    const float* c1w = (const float*)d_in[1];
    const float* c1b = (const float*)d_in[2];
    const float* c2w = (const float*)d_in[3];
    const float* c2b = (const float*)d_in[4];
    const float* c3w = (const float*)d_in[5];
    const float* c3b = (const float*)d_in[6];
    const float* c4w = (const float*)d_in[7];
    const float* c4b = (const float*)d_in[8];
    const float* epw1 = (const float*)d_in[9];
    const float* epb1 = (const float*)d_in[10];
    const float* epw2 = (const float*)d_in[11];
    const float* epb2 = (const float*)d_in[12];
    const float* cnw1 = (const float*)d_in[13];
    const float* cnb1 = (const float*)d_in[14];
    const float* cnw2 = (const float*)d_in[15];
    const float* cnb2 = (const float*)d_in[16];

    const int B = in_sizes[0] / (32 * 32);  // 1024

    unsigned short* ws = (unsigned short*)d_ws;
    unsigned short* embo = ws;                            // B*256 bf16
    unsigned short* wp2 = embo + (size_t)B * 256;         // 25600
    unsigned short* wp3 = wp2 + 25600;                    // 51200
    unsigned short* wp4 = wp3 + 51200;                    // 102400
    unsigned short* wph1 = wp4 + 102400;                  // 131072
    unsigned short* wpcn2 = wph1 + 131072;                // 32768
    unsigned short* wpep2 = wpcn2 + 32768;                // 12288
    unsigned short* wp1 = wpep2 + 12288;                  // 1024

    k_prepall<<<1392, 256, 0, stream>>>(c1w, c2w, c3w, c4w, cnw1, epw1, cnw2, epw2,
                                        wp1, wp2, wp3, wp4, wph1, wpcn2, wpep2);
    k_convall<<<B, 512, 0, stream>>>(image, c1b, wp1, wp2, c2b, wp3, c3b, wp4, c4b, embo);
    k_heads<<<B / 16, 256, 0, stream>>>(embo, wph1, cnb1, epb1,
                                        wpcn2, cnb2, wpep2, epb2, (float*)d_out);
}

// Round 12
// 170.684 us; speedup vs baseline: 1.0651x; 1.0651x over previous
//
#include <hip/hip_runtime.h>
#include <math.h>

typedef __attribute__((ext_vector_type(8))) short short8;
typedef __attribute__((ext_vector_type(4))) float float4v;
typedef __attribute__((ext_vector_type(4))) unsigned short ushort4v;

static __device__ __forceinline__ unsigned short f2bf(float f) {
    union { float f; unsigned u; } v; v.f = f;
    unsigned u = v.u;
    return (unsigned short)((u + 0x7fffu + ((u >> 16) & 1u)) >> 16);
}
static __device__ __forceinline__ float bf2f(unsigned short h) {
    union { unsigned u; float f; } v; v.u = ((unsigned)h) << 16;
    return v.f;
}
static __device__ __forceinline__ unsigned pk2(float a, float b) {
    return (unsigned)f2bf(a) | ((unsigned)f2bf(b) << 16);
}
// XOR-swizzled address into [pos][32] bf16 rows (8-ushort chunks):
// chunk c at row pos lives at physical chunk (c ^ pos) & 3. Returns ushort idx.
static __device__ __forceinline__ int swz(int pos, int chunk) {
    return (pos << 5) + (((chunk ^ pos) & 3) << 3);
}

// ---------------------------------------------------------------------------
// Graph structure (compile-time), matching Python enumeration order.
// ---------------------------------------------------------------------------
struct AdjT {
    int src[120];
    int dst[120];
    int cnt[36];
    int idx[36][4];
    int ostart[36];
    int ocnt[36];
};

constexpr AdjT build_adj() {
    AdjT a{};
    const int ddx[4] = {-1, 0, 0, 1};
    const int ddy[4] = {0, -1, 1, 0};
    int ne = 0;
    for (int i = 0; i < 6; i++)
        for (int j = 0; j < 6; j++)
            for (int d = 0; d < 4; d++) {
                int x = i + ddx[d], y = j + ddy[d];
                if (x >= 0 && x < 6 && y >= 0 && y < 6) {
                    a.src[ne] = j * 6 + i;
                    a.dst[ne] = y * 6 + x;
                    ne++;
                }
            }
    for (int n = 0; n < 36; n++) {
        a.cnt[n] = 0;
        for (int e = 0; e < 120; e++)
            if (a.dst[e] == n) a.idx[n][a.cnt[n]++] = e;
    }
    for (int n = 0; n < 36; n++) { a.ostart[n] = 0; a.ocnt[n] = 0; }
    for (int e = 0; e < 120; e++) {
        a.ocnt[a.src[e]]++;
        if (e == 0 || a.src[e] != a.src[e - 1]) a.ostart[a.src[e]] = e;
    }
    return a;
}

__device__ constexpr AdjT ADJC = build_adj();
__device__ constexpr int G16_START[17] =
    {0, 3, 6, 9, 12, 14, 16, 18, 20, 22, 24, 26, 28, 30, 32, 34, 36};

// ---------------------------------------------------------------------------
// K0: merged weight prep (verified R9-R11). Column-interleaved conv B-frags.
// ---------------------------------------------------------------------------
__global__ __launch_bounds__(256) void k_prepall(
    const float* __restrict__ w1, const float* __restrict__ w2,
    const float* __restrict__ w3, const float* __restrict__ w4,
    const float* __restrict__ cnw1, const float* __restrict__ epw1,
    const float* __restrict__ cnw2, const float* __restrict__ epw2,
    unsigned short* __restrict__ wp1, unsigned short* __restrict__ wp2,
    unsigned short* __restrict__ wp3, unsigned short* __restrict__ wp4,
    unsigned short* __restrict__ wph1, unsigned short* __restrict__ wpcn2,
    unsigned short* __restrict__ wpep2) {
    int e = blockIdx.x * 256 + threadIdx.x;
    if (e < 180224) {
        if (e < 25600) {
            int j = e & 7, lane = (e >> 3) & 63, ct = (e >> 9) & 1, t = e >> 10;
            int co = 2 * (lane & 15) + ct, ci = (lane >> 4) * 8 + j;
            wp2[e] = f2bf(w2[co * 800 + ci * 25 + t]);
        } else if (e < 76800) {
            int e3 = e - 25600;
            int j = e3 & 7, lane = (e3 >> 3) & 63, nt = (e3 >> 9) & 3, t = e3 >> 11;
            int co = 4 * (lane & 15) + nt, ci = (lane >> 4) * 8 + j;
            wp3[e3] = f2bf(w3[(co * 32 + ci) * 25 + t]);
        } else if (e < 179200) {
            int e4 = e - 76800;
            int j = e4 & 7, lane = (e4 >> 3) & 63, nt = (e4 >> 9) & 3;
            int ks = (e4 >> 11) & 1, t = e4 >> 12;
            int co = 4 * (lane & 15) + nt, ci = ks * 32 + (lane >> 4) * 8 + j;
            wp4[e4] = f2bf(w4[(co * 64 + ci) * 25 + t]);
        } else {
            int e1 = e - 179200;
            int j = e1 & 7, lane = (e1 >> 3) & 63, nt = (e1 >> 9) & 1;
            int n = lane & 15, q = lane >> 4;
            int k = q * 8 + j;
            int co = 2 * n + nt;
            wp1[e1] = (k < 25) ? f2bf(w1[co * 25 + k]) : (unsigned short)0;
        }
    } else {
        int eh = e - 180224;
        if (eh < 131072) {
            int j = eh & 7, lane = (eh >> 3) & 63, nt = (eh >> 9) & 31, kt = eh >> 14;
            int c = nt * 16 + (lane & 15);
            int k = kt * 32 + ((lane >> 4) << 3) + j;
            float v = (c < 256) ? cnw1[c * 256 + k] : epw1[(c - 256) * 256 + k];
            wph1[eh] = f2bf(v);
        } else if (eh < 163840) {
            int e2 = eh - 131072;
            int j = e2 & 7, lane = (e2 >> 3) & 63, nt = (e2 >> 9) & 7, kt = e2 >> 12;
            int c = nt * 16 + (lane & 15);
            int k = kt * 32 + ((lane >> 4) << 3) + j;
            wpcn2[e2] = f2bf(c < 120 ? cnw2[c * 256 + k] : 0.f);
        } else {
            int e3 = eh - 163840;
            int j = e3 & 7, lane = (e3 >> 3) & 63, idx = e3 >> 9;
            int kt = idx / 3, nt = idx - kt * 3;
            int c = nt * 16 + (lane & 15);
            int k = kt * 32 + ((lane >> 4) << 3) + j;
            wpep2[e3] = f2bf(c < 36 ? epw2[c * 256 + k] : 0.f);
        }
    }
}

// ---------------------------------------------------------------------------
// K_CONVALL: whole CNN in one kernel. R12: same as R11 (XOR swizzle, bf16
// image, 51.3 KB LDS -> 3 blocks/CU) but WITHOUT the min-waves launch-bounds
// hint — R11's (512,6) forced VGPR to 40 and spilled 60 MB/dispatch to
// scratch (WRITE_SIZE 41 MB). Plain (512) compiled this phase code at 52
// VGPR in R10 -> supports 8 waves/SIMD naturally, no spills.
// ---------------------------------------------------------------------------
__global__ __launch_bounds__(512) void k_convall(
    const float* __restrict__ img, const float* __restrict__ b1,
    const unsigned short* __restrict__ wp1,
    const unsigned short* __restrict__ wp2, const float* __restrict__ b2,
    const unsigned short* __restrict__ wp3, const float* __restrict__ b3,
    const unsigned short* __restrict__ wp4, const float* __restrict__ b4,
    unsigned short* __restrict__ emb) {
    __shared__ unsigned short s_imgbf[32 * 36];
    __shared__ unsigned short s_buf[25088];
    const int b = blockIdx.x, tid = threadIdx.x;
    const int lane = tid & 63, wave = tid >> 6;
    const int m = lane & 15, quad = lane >> 4;
    const int P2O = 18432;

    // stage full image as bf16 (first 256 threads, float4 -> 4x bf16 b64 write)
    if (tid < 256) {
        float4 t = ((const float4*)(img + (size_t)b * 1024))[tid];
        ushort4v pkv;
        pkv[0] = f2bf(t.x); pkv[1] = f2bf(t.y);
        pkv[2] = f2bf(t.z); pkv[3] = f2bf(t.w);
        *(ushort4v*)(s_imgbf + (tid >> 3) * 36 + (tid & 7) * 4) = pkv;
    }

    // conv1 B-frags + per-lane tap gather offsets (K=25 pad 32)
    short8 w1b0 = ((const short8*)wp1)[lane];
    short8 w1b1 = ((const short8*)wp1)[64 + lane];
    const float c1b0 = b1[2 * m], c1b1 = b1[2 * m + 1];
    int toff1[8];
    unsigned short vm1[8];
#pragma unroll
    for (int j = 0; j < 8; j++) {
        int k = quad * 8 + j;
        int kk = (k < 25) ? k : 0;
        int ky = kk / 5, kx = kk - ky * 5;
        toff1[j] = ky * 36 + kx;
        vm1[j] = (k < 25) ? (unsigned short)0xFFFFu : (unsigned short)0;
    }
    // conv2 B-frag prefetch
    const short8* wq2 = (const short8*)wp2;
    short8 bw0 = wq2[lane];
    short8 bw1 = wq2[64 + lane];

    __syncthreads();

    // ---- conv1 via MFMA: 49 Mtiles, stride 8 over waves; swizzled staging ----
    for (int mt = wave; mt < 49; mt += 8) {
        int pos = mt * 16 + m;
        int y = pos / 28, x = pos - y * 28;
        const unsigned short* wb = s_imgbf + y * 36 + x;
        short8 av;
#pragma unroll
        for (int j = 0; j < 8; j++)
            av[j] = (short)(wb[toff1[j]] & vm1[j]);
        float4v a0 = {c1b0, c1b0, c1b0, c1b0};
        float4v a1 = {c1b1, c1b1, c1b1, c1b1};
        a0 = __builtin_amdgcn_mfma_f32_16x16x32_bf16(av, w1b0, a0, 0, 0, 0);
        a1 = __builtin_amdgcn_mfma_f32_16x16x32_bf16(av, w1b1, a1, 0, 0, 0);
        int pb = mt * 16 + quad * 4;
#pragma unroll
        for (int r = 0; r < 4; r++) {
            int row = pb + r;
            *(unsigned*)(s_buf + swz(row, m >> 2) + ((m & 3) << 1)) = pk2(a0[r], a1[r]);
        }
    }
    __syncthreads();

    // ---- conv2 tap-GEMM: 36 Mtiles -> waves 0-3: 5, waves 4-7: 4 ----
    const int nm2 = (wave < 4) ? 5 : 4;
    int bp[5];
#pragma unroll
    for (int i9 = 0; i9 < 5; i9++) {
        int M = i9 * 8 + wave;
        if (M > 35) M = 35;
        int p = M * 16 + m;
        int y2 = p / 24, x2 = p - y2 * 24;
        bp[i9] = y2 * 28 + x2;
    }
    float4v acc[5][2];
#pragma unroll
    for (int i9 = 0; i9 < 5; i9++) {
        acc[i9][0] = (float4v){0.f, 0.f, 0.f, 0.f};
        acc[i9][1] = (float4v){0.f, 0.f, 0.f, 0.f};
    }
    for (int t = 0; t < 25; t++) {
        short8 nb0, nb1;
        if (t < 24) {
            nb0 = wq2[(t + 1) * 128 + lane];
            nb1 = wq2[(t + 1) * 128 + 64 + lane];
        }
        const int ky = t / 5, kx = t - ky * 5;
        const int tp = ky * 28 + kx;
#pragma unroll
        for (int i9 = 0; i9 < 5; i9++) {
            if (i9 < nm2) {
                int p = bp[i9] + tp;
                short8 av = *(const short8*)(s_buf + swz(p, quad));
                acc[i9][0] = __builtin_amdgcn_mfma_f32_16x16x32_bf16(av, bw0, acc[i9][0], 0, 0, 0);
                acc[i9][1] = __builtin_amdgcn_mfma_f32_16x16x32_bf16(av, bw1, acc[i9][1], 0, 0, 0);
            }
        }
        if (t < 24) { bw0 = nb0; bw1 = nb1; }
    }
    __syncthreads();  // all conv2 A-reads done before stage overwrites

    // stage conv2 out: packed b32, swizzled [pos2][co]
#pragma unroll
    for (int i9 = 0; i9 < 5; i9++) {
        if (i9 < nm2) {
            int pb2 = (i9 * 8 + wave) * 16 + quad * 4;
#pragma unroll
            for (int r = 0; r < 4; r++) {
                int row = pb2 + r;
                *(unsigned*)(s_buf + swz(row, m >> 2) + ((m & 3) << 1)) =
                    pk2(acc[i9][0][r], acc[i9][1][r]);
            }
        }
    }
    __syncthreads();

    // pool 2x2 + bias2 -> p2 [144][40] plain at P2O
    for (int i = tid; i < 4608; i += 512) {
        int co = i & 31, pos12 = i >> 5;
        int prl = pos12 / 12, px = pos12 - prl * 12;
        int p00 = (prl * 2) * 24 + px * 2;
        int ch = co >> 3, cw = co & 7;
        float v0 = bf2f(s_buf[swz(p00, ch) + cw]);
        float v1 = bf2f(s_buf[swz(p00 + 1, ch) + cw]);
        float v2 = bf2f(s_buf[swz(p00 + 24, ch) + cw]);
        float v3 = bf2f(s_buf[swz(p00 + 25, ch) + cw]);
        float mx = fmaxf(fmaxf(v0, v1), fmaxf(v2, v3));
        s_buf[P2O + pos12 * 40 + co] = f2bf(mx + b2[co]);
    }
    __syncthreads();

    // ---- conv3: Mtile = wave>>1 (pos3 in 8x8 grid), Ntile half = wave&1 ----
    {
        int pos3 = (wave >> 1) * 16 + m;
        int y3 = pos3 >> 3, x3 = pos3 & 7;
        int a3 = P2O + (y3 * 12 + x3) * 40 + quad * 8;
        int nt0 = (wave & 1) * 2;
        float4v acc3[2];
        acc3[0] = (float4v){0.f, 0.f, 0.f, 0.f};
        acc3[1] = (float4v){0.f, 0.f, 0.f, 0.f};
        const short8* wq3 = (const short8*)wp3;
        short8 bw3[2];
        bw3[0] = wq3[nt0 * 64 + lane];
        bw3[1] = wq3[(nt0 + 1) * 64 + lane];
        for (int t = 0; t < 25; t++) {
            short8 nb3[2];
            if (t < 24) {
                nb3[0] = wq3[((t + 1) * 4 + nt0) * 64 + lane];
                nb3[1] = wq3[((t + 1) * 4 + nt0 + 1) * 64 + lane];
            }
            const int ky = t / 5, kx = t - ky * 5;
            short8 av = *(const short8*)(s_buf + a3 + (ky * 12 + kx) * 40);
            acc3[0] = __builtin_amdgcn_mfma_f32_16x16x32_bf16(av, bw3[0], acc3[0], 0, 0, 0);
            acc3[1] = __builtin_amdgcn_mfma_f32_16x16x32_bf16(av, bw3[1], acc3[1], 0, 0, 0);
            if (t < 24) { bw3[0] = nb3[0]; bw3[1] = nb3[1]; }
        }
        // stage s_c3 [64][72] (+bias3) at [0,4608): disjoint from p2 region.
        float bb0 = b3[4 * m + nt0], bb1 = b3[4 * m + nt0 + 1];
#pragma unroll
        for (int r = 0; r < 4; r++) {
            int row3 = (wave >> 1) * 16 + quad * 4 + r;
            *(unsigned*)(s_buf + row3 * 72 + 4 * m + nt0) =
                pk2(acc3[0][r] + bb0, acc3[1][r] + bb1);
        }
    }
    __syncthreads();

    // ---- conv4: waves 0-3 (Ntile = wave, 2 Ksteps); waves 4-7 idle ----
    if (wave < 4) {
        int y4 = m >> 2, x4 = m & 3;
        int a4 = (y4 * 8 + x4) * 72 + quad * 8;
        float4v acc4 = (float4v){0.f, 0.f, 0.f, 0.f};
        const short8* wq4 = (const short8*)wp4;
        short8 cw0 = wq4[(0 * 4 + wave) * 64 + lane];
        short8 cw1 = wq4[(1 * 4 + wave) * 64 + lane];
        for (int t = 0; t < 25; t++) {
            short8 n0, n1;
            if (t < 24) {
                n0 = wq4[(((t + 1) * 2) * 4 + wave) * 64 + lane];
                n1 = wq4[(((t + 1) * 2 + 1) * 4 + wave) * 64 + lane];
            }
            const int ky = t / 5, kx = t - ky * 5;
            const int toff = (ky * 8 + kx) * 72;
            short8 av0 = *(const short8*)(s_buf + a4 + toff);
            acc4 = __builtin_amdgcn_mfma_f32_16x16x32_bf16(av0, cw0, acc4, 0, 0, 0);
            short8 av1 = *(const short8*)(s_buf + a4 + toff + 32);
            acc4 = __builtin_amdgcn_mfma_f32_16x16x32_bf16(av1, cw1, acc4, 0, 0, 0);
            if (t < 24) { cw0 = n0; cw1 = n1; }
        }
        // s_c4 f32 [16][68] at ushort 8192 — disjoint from s_c3 [0,4608)
        float* s_c4 = (float*)(s_buf + 8192);
#pragma unroll
        for (int r = 0; r < 4; r++)
            s_c4[(quad * 4 + r) * 68 + 4 * m + wave] = acc4[r];
    }
    __syncthreads();

    // emb epilogue: tid = co*4 + pp; pool 2x2 + bias4 + flatten
    if (tid < 256) {
        const float* s_c4 = (const float*)(s_buf + 8192);
        int co = tid >> 2, pp = tid & 3;
        int ppy = pp >> 1, ppx = pp & 1;
        float v0 = s_c4[((2 * ppy) * 4 + 2 * ppx) * 68 + co];
        float v1 = s_c4[((2 * ppy) * 4 + 2 * ppx + 1) * 68 + co];
        float v2 = s_c4[((2 * ppy + 1) * 4 + 2 * ppx) * 68 + co];
        float v3 = s_c4[((2 * ppy + 1) * 4 + 2 * ppx + 1) * 68 + co];
        emb[(size_t)b * 256 + tid] =
            f2bf(fmaxf(fmaxf(v0, v1), fmaxf(v2, v3)) + b4[co]);
    }
}

// ---------------------------------------------------------------------------
// K5: fused heads (MFMA) + DAMP recurrence (verified R4-R11).
// Phase-3 uses wave-local sync (all comm intra-wave; row = tid>>4).
// ---------------------------------------------------------------------------
__global__ __launch_bounds__(256) void k_heads(
    const unsigned short* __restrict__ emb,
    const unsigned short* __restrict__ wph1,
    const float* __restrict__ cn_b1, const float* __restrict__ ep_b1,
    const unsigned short* __restrict__ wpcn2, const float* __restrict__ cn_b2,
    const unsigned short* __restrict__ wpep2, const float* __restrict__ ep_b2,
    float* __restrict__ out) {
    __shared__ unsigned short s_hid[16 * 520];
    __shared__ float s_conn[120 * 17];
    __shared__ float s_rec0[120 * 17];
    __shared__ float s_rec1[120 * 17];
    __shared__ float s_ep[36 * 17];
    const int tid = threadIdx.x;
    const int lane = tid & 63, wave = tid >> 6;
    const int m = lane & 15, q = lane >> 4;
    const int b0 = blockIdx.x * 16;

    float4v acc[8];
#pragma unroll
    for (int i = 0; i < 8; i++) acc[i] = (float4v){0.f, 0.f, 0.f, 0.f};
    const short8* wp1 = (const short8*)wph1;
    for (int kt = 0; kt < 8; kt++) {
        short8 av = *(const short8*)(emb + (size_t)(b0 + m) * 256 + kt * 32 + q * 8);
#pragma unroll
        for (int ntl = 0; ntl < 8; ntl++) {
            int nt = wave * 8 + ntl;
            short8 bv = wp1[(kt * 32 + nt) * 64 + lane];
            acc[ntl] = __builtin_amdgcn_mfma_f32_16x16x32_bf16(av, bv, acc[ntl], 0, 0, 0);
        }
    }
#pragma unroll
    for (int ntl = 0; ntl < 8; ntl++) {
        int c = (wave * 8 + ntl) * 16 + m;
        float bb = (c < 256) ? cn_b1[c] : ep_b1[c - 256];
#pragma unroll
        for (int r = 0; r < 4; r++)
            s_hid[(q * 4 + r) * 520 + c] = f2bf(fmaxf(acc[ntl][r] + bb, 0.f));
    }
    __syncthreads();

    for (int job = wave; job < 11; job += 4) {
        const bool isconn = job < 8;
        const int koff = isconn ? 0 : 256;
        float4v a2 = (float4v){0.f, 0.f, 0.f, 0.f};
        for (int kt = 0; kt < 8; kt++) {
            short8 av = *(const short8*)(s_hid + m * 520 + koff + kt * 32 + q * 8);
            short8 bv = isconn
                ? ((const short8*)wpcn2)[(kt * 8 + job) * 64 + lane]
                : ((const short8*)wpep2)[(kt * 3 + (job - 8)) * 64 + lane];
            a2 = __builtin_amdgcn_mfma_f32_16x16x32_bf16(av, bv, a2, 0, 0, 0);
        }
        int c = (isconn ? job : (job - 8)) * 16 + m;
        float bb = isconn ? (c < 120 ? cn_b2[c] : 0.f) : (c < 36 ? ep_b2[c] : 0.f);
#pragma unroll
        for (int r = 0; r < 4; r++) {
            float v = 1.f / (1.f + __expf(-(a2[r] + bb)));
            int row = q * 4 + r;
            if (isconn) {
                if (c < 120) { s_conn[c * 17 + row] = v; s_rec0[c * 17 + row] = v; }
            } else {
                if (c < 36) s_ep[c * 17 + row] = v;
            }
        }
    }
    __syncthreads();

    const int row = tid >> 4, g = tid & 15;
    const int ns = G16_START[g];
    const int nodecnt = G16_START[g + 1] - ns;
    int ie[3][4], icnt[3], os[3], oc[3];
    float cr[3][4];
#pragma unroll
    for (int s = 0; s < 3; s++) {
        if (s < nodecnt) {
            int n = ns + s;
            icnt[s] = ADJC.cnt[n];
#pragma unroll
            for (int qx = 0; qx < 4; qx++) ie[s][qx] = ADJC.idx[n][qx];
            os[s] = ADJC.ostart[n];
            oc[s] = ADJC.ocnt[n];
#pragma unroll
            for (int oe = 0; oe < 4; oe++)
                cr[s][oe] = (oe < oc[s]) ? s_conn[(os[s] + oe) * 17 + row] : 0.f;
        } else {
            icnt[s] = 0; oc[s] = 0; os[s] = 0;
#pragma unroll
            for (int qx = 0; qx < 4; qx++) ie[s][qx] = 0;
#pragma unroll
            for (int oe = 0; oe < 4; oe++) cr[s][oe] = 0.f;
        }
    }
    float old0 = (g == 0) ? s_conn[0 * 17 + row] : 0.f;

    for (int it = 0; it < 36; it++) {
        const float* cur = (it & 1) ? s_rec1 : s_rec0;
        float* nxt = (it & 1) ? s_rec0 : s_rec1;
#pragma unroll
        for (int s = 0; s < 3; s++) {
            float sum = 0.f;
#pragma unroll
            for (int qx = 0; qx < 4; qx++)
                sum += (qx < icnt[s]) ? cur[ie[s][qx] * 17 + row] : 0.f;
            sum = fminf(sum, 1.f);
#pragma unroll
            for (int oe = 0; oe < 4; oe++) {
                if (oe < oc[s]) {
                    int e = os[s] + oe;
                    float nv = sum * cr[s][oe];
                    nxt[e * 17 + row] = nv;
                    if (g == 0 && s == 0 && oe == 0)
                        old0 = fminf(old0 + nv, 1.f);
                }
            }
        }
        __asm__ volatile("s_waitcnt lgkmcnt(0)" ::: "memory");
    }

    if (g == 0)
        out[b0 + row] = old0 * s_ep[0 * 17 + row] * s_ep[6 * 17 + row];
}

// ---------------------------------------------------------------------------
extern "C" void kernel_launch(void* const* d_in, const int* in_sizes, int n_in,
                              void* d_out, int out_size, void* d_ws, size_t ws_size,
                              hipStream_t stream) {
    const float* image = (const float*)d_in[0];
    const float* c1w = (const float*)d_in[1];
    const float* c1b = (const float*)d_in[2];
    const float* c2w = (const float*)d_in[3];
    const float* c2b = (const float*)d_in[4];
    const float* c3w = (const float*)d_in[5];
    const float* c3b = (const float*)d_in[6];
    const float* c4w = (const float*)d_in[7];
    const float* c4b = (const float*)d_in[8];
    const float* epw1 = (const float*)d_in[9];
    const float* epb1 = (const float*)d_in[10];
    const float* epw2 = (const float*)d_in[11];
    const float* epb2 = (const float*)d_in[12];
    const float* cnw1 = (const float*)d_in[13];
    const float* cnb1 = (const float*)d_in[14];
    const float* cnw2 = (const float*)d_in[15];
    const float* cnb2 = (const float*)d_in[16];

    const int B = in_sizes[0] / (32 * 32);  // 1024

    unsigned short* ws = (unsigned short*)d_ws;
    unsigned short* embo = ws;                            // B*256 bf16
    unsigned short* wp2 = embo + (size_t)B * 256;         // 25600
    unsigned short* wp3 = wp2 + 25600;                    // 51200
    unsigned short* wp4 = wp3 + 51200;                    // 102400
    unsigned short* wph1 = wp4 + 102400;                  // 131072
    unsigned short* wpcn2 = wph1 + 131072;                // 32768
    unsigned short* wpep2 = wpcn2 + 32768;                // 12288
    unsigned short* wp1 = wpep2 + 12288;                  // 1024

    k_prepall<<<1392, 256, 0, stream>>>(c1w, c2w, c3w, c4w, cnw1, epw1, cnw2, epw2,
                                        wp1, wp2, wp3, wp4, wph1, wpcn2, wpep2);
    k_convall<<<B, 512, 0, stream>>>(image, c1b, wp1, wp2, c2b, wp3, c3b, wp4, c4b, embo);
    k_heads<<<B / 16, 256, 0, stream>>>(embo, wph1, cnb1, epb1,
                                        wpcn2, cnb2, wpep2, epb2, (float*)d_out);
}